// Round 12
// baseline (123.486 us; speedup 1.0000x reference)
//
#include <hip/hip_runtime.h>
#include <stdint.h>

// N=4096, D=1024 -> M = [Q|K] : 4096 x 2048, Mt = M^T (fp8 e4m3, K-permuted)
// loss = [ sum_{a,b} s_a s_b (M^T M)_ab^2 ] / (N*(N-1)), s_a=+1 (a<1024), -1 else
// R12: 256x256 fp8 gram tiles (staged bytes 143->75.5 MB; gram is staging-BW
// bound at ~6.3 TB/s across R1..R11). 512-thr/8-wave blocks, wave tile 64x128,
// B-frags streamed in j-loop (~185 VGPR, fixes R10 spill), LDS 64KiB/iter
// double-buffered (128 KiB, 1 block/CU — dbuf is the only overlap mechanism
// at 1 block/CU; R7 proved it redundant only at 2 blocks/CU). KSPLIT=8.
#define N_ROWS 4096
#define DIMS   1024
#define BM 256         // gram tile (square), 8-grid
#define TG 8
#define NTRI 36        // 8*9/2
#define KSPLIT 8
#define KCHUNK 512     // 4096/KSPLIT (fp8 bytes)
#define BKB 128        // staged bytes per row per iteration (one K-perm block)
#define NITER 4        // KCHUNK/BKB
#define NJOBS (NTRI * KSPLIT)  // 288

typedef __attribute__((ext_vector_type(2))) long longx2;
typedef __attribute__((ext_vector_type(8))) unsigned short ushort8;
typedef __attribute__((ext_vector_type(4))) float f32x4;

__device__ __forceinline__ unsigned short f2bf(float f) {
  union { float f; unsigned int u; } c; c.f = f;
  unsigned int u = c.u;
  return (unsigned short)((u + 0x7fffu + ((u >> 16) & 1u)) >> 16);
}
__device__ __forceinline__ float bf2f(unsigned short v) {
  union { float f; unsigned int u; } c; c.u = ((unsigned int)v) << 16;
  return c.f;
}
__device__ __forceinline__ unsigned int pk4_fp8(float a, float b, float c, float d) {
  int v = __builtin_amdgcn_cvt_pk_fp8_f32(a, b, 0, false);
  v = __builtin_amdgcn_cvt_pk_fp8_f32(c, d, v, true);
  return (unsigned int)v;
}
// async global->LDS, 16B/lane; LDS dest = wave-uniform base + lane*16
__device__ __forceinline__ void async_cp16(const unsigned char* g, void* lds) {
  __builtin_amdgcn_global_load_lds(
      (const __attribute__((address_space(1))) void*)g,
      (__attribute__((address_space(3))) void*)lds, 16, 0, 0);
}

// ---------------------------------------------------------------------------
// K1: inverse row norms; zero d_out. (R6/R11-verified)
// ---------------------------------------------------------------------------
__global__ __launch_bounds__(256) void rownorm_kernel(
    const float* __restrict__ fq, const float* __restrict__ fk,
    float* __restrict__ invq, float* __restrict__ invk, float* __restrict__ out) {
  if (blockIdx.x == 0 && blockIdx.y == 0 && threadIdx.x == 0) out[0] = 0.0f;
  const int w = threadIdx.x >> 6, lane = threadIdx.x & 63;
  const int row = blockIdx.x * 4 + w;
  const float* src = blockIdx.y ? fk : fq;
  float* dst = blockIdx.y ? invk : invq;
  const float4* s4 = (const float4*)(src + (size_t)row * DIMS);
  float ss = 0.0f;
  #pragma unroll
  for (int s = 0; s < 4; ++s) {
    float4 v = s4[lane + 64 * s];
    ss += v.x * v.x + v.y * v.y + v.z * v.z + v.w * v.w;
  }
  #pragma unroll
  for (int off = 32; off > 0; off >>= 1) ss += __shfl_xor(ss, off);
  if (lane == 0) dst[row] = 1.0f / sqrtf(ss);  // eps terms cancel (~3e-9 rel)
}

// ---------------------------------------------------------------------------
// K2: Mt[a][perm(i)] = fp8(normalized), transposed via LDS. (R6/R11-verified)
// K-perm: i = s1*64+s0*32+q*8+j -> pos = q*32+s1*16+s0*8+j within 128-block.
// ---------------------------------------------------------------------------
__global__ __launch_bounds__(256) void transpose_scale_kernel(
    const float* __restrict__ fq, const float* __restrict__ fk,
    const float* __restrict__ invq, const float* __restrict__ invk,
    unsigned char* __restrict__ Mt) {
  __shared__ unsigned short tile[64][260];
  const int i0 = blockIdx.x * 256;
  const int a0 = blockIdx.y * 64;
  const int w = threadIdx.x >> 6, lane = threadIdx.x & 63;
  const float* src;
  const float* inv;
  int acol;
  if (a0 < DIMS) { src = fq; inv = invq; acol = a0 + lane; }
  else           { src = fk; inv = invk; acol = a0 - DIMS + lane; }

  for (int c0 = 0; c0 < 64; c0 += 4) {
    ushort4 v;
    unsigned short* vp = (unsigned short*)&v;
    #pragma unroll
    for (int c = 0; c < 4; ++c) {
      const int i = i0 + w * 64 + c0 + c;
      vp[c] = f2bf(src[(size_t)i * DIMS + acol] * inv[i]);
    }
    *(ushort4*)&tile[lane][w * 64 + c0] = v;
  }
  __syncthreads();
  const int il = (lane * 4) & 127;
  const int blk = (i0 + lane * 4) >> 7;
  const int q = (il >> 3) & 3, s0b = (il >> 5) & 1, s1b = (il >> 6) & 1;
  const int pos = q * 32 + s1b * 16 + s0b * 8 + (il & 7);
  #pragma unroll
  for (int r = 0; r < 16; ++r) {
    const int al = w * 16 + r;
    ushort4 v = *(const ushort4*)&tile[al][lane * 4];
    const unsigned int p8 = pk4_fp8(bf2f(v.x), bf2f(v.y), bf2f(v.z), bf2f(v.w));
    *(unsigned int*)(Mt + (size_t)(a0 + al) * N_ROWS + blk * 128 + pos) = p8;
  }
}

// ---------------------------------------------------------------------------
// K3: 256x256 partial Gram, fp8 MFMA, 512 threads (8 waves), dbuf LDS.
// Waves 0-3 stage A panel quarters; 4-7 stage B (diag: B aliases A).
// Compute: wave (w>>1, w&1) owns 64x128. B-frags streamed per j.
// ---------------------------------------------------------------------------
__global__ __launch_bounds__(512, 1) void gram_partial_kernel(
    const unsigned char* __restrict__ Mt, unsigned short* __restrict__ Gp) {
  __shared__ __align__(16) char smem[2][2 * BM * BKB];  // 2 x 64 KiB

  const int t = blockIdx.x >> 3;
  const int kc = blockIdx.x & 7;
  int I = 0, rem = t;
  while (rem >= (TG - I)) { rem -= (TG - I); ++I; }
  const int J = I + rem;

  const int tid = threadIdx.x, w = tid >> 6, lane = tid & 63;

  // staging role
  const int isB = w >> 2;
  const int wq = w & 3;                 // quarter of the 256-row panel
  const int rblk = isB ? J : I;
  const int rl = lane >> 3;
  const int cl = (lane & 7) ^ rl;       // chunk swizzle (verified R1..R11)
  const bool skipStage = (isB && I == J);
  const unsigned char* gsrc0 =
      Mt + (size_t)(rblk * BM + wq * 64 + rl) * N_ROWS + kc * KCHUNK + cl * 16;
  const int ldsOff = isB * 32768 + wq * 8192;
  const int bOff = (I == J) ? 0 : 32768;

  // compute role: wave tile 64 x 128
  const int ml = lane & 15, quad = lane >> 4;
  const int ar0 = (w >> 1) * 64, bc0 = (w & 1) * 128;

  f32x4 acc[4][8] = {};

  // prologue: stage chunk 0 into buffer 0
  if (!skipStage) {
    #pragma unroll
    for (int s = 0; s < 8; ++s)
      async_cp16(gsrc0 + (size_t)s * 8 * N_ROWS, smem[0] + ldsOff + s * 1024);
  }

  for (int it = 0; it < NITER; ++it) {
    __syncthreads();  // drains stage(it); orders prior reads vs new writes
    if (it + 1 < NITER && !skipStage) {
      const unsigned char* g = gsrc0 + (it + 1) * BKB;
      char* dst = smem[(it + 1) & 1] + ldsOff;
      #pragma unroll
      for (int s = 0; s < 8; ++s)
        async_cp16(g + (size_t)s * 8 * N_ROWS, dst + s * 1024);
    }
    const char* buf = smem[it & 1];

    // A-frags for this iter (kept live: 32 VGPRs)
    longx2 a[4][2];
    #pragma unroll
    for (int i = 0; i < 4; ++i)
      #pragma unroll
      for (int s1 = 0; s1 < 2; ++s1) {
        const int slot = ((quad * 2 + s1) ^ (ml & 7)) * 16;
        a[i][s1] = *(const longx2*)(buf + (ar0 + i * 16 + ml) * BKB + slot);
      }
    // stream B-frags per output column block j (8 VGPRs live)
    #pragma unroll
    for (int j = 0; j < 8; ++j) {
      longx2 b[2];
      #pragma unroll
      for (int s1 = 0; s1 < 2; ++s1) {
        const int slot = ((quad * 2 + s1) ^ (ml & 7)) * 16;
        b[s1] = *(const longx2*)(buf + bOff + (bc0 + j * 16 + ml) * BKB + slot);
      }
      #pragma unroll
      for (int s1 = 0; s1 < 2; ++s1)
        #pragma unroll
        for (int h = 0; h < 2; ++h)
          #pragma unroll
          for (int i = 0; i < 4; ++i)
            acc[i][j] = __builtin_amdgcn_mfma_f32_16x16x32_fp8_fp8(
                a[i][s1][h], b[s1][h], acc[i][j], 0, 0, 0);
    }
  }

  // epilogue: lane-major coalesced bf16 slab.
  // entry: w*8192 + (i*8+j)*256 + lane*4 + p
  // decode: r=(w>>1)*64+i*16+(lane>>4)*4+p, c=(w&1)*128+j*16+(lane&15)
  unsigned short* slab = Gp + (size_t)blockIdx.x * (BM * BM) + w * 8192;
  #pragma unroll
  for (int i = 0; i < 4; ++i)
    #pragma unroll
    for (int j = 0; j < 8; ++j) {
      ushort4 o;
      o.x = f2bf(acc[i][j][0]); o.y = f2bf(acc[i][j][1]);
      o.z = f2bf(acc[i][j][2]); o.w = f2bf(acc[i][j][3]);
      *(ushort4*)(slab + (i * 8 + j) * 256 + lane * 4) = o;
    }
}

// ---------------------------------------------------------------------------
// K4: sum KSPLIT partials (fp32), square, weight by decoded (gr,gc) for diag
// tiles, sign by block, reduce -> atomicAdd. Grid: NTRI*32, 2048 entries/blk.
// ---------------------------------------------------------------------------
__global__ __launch_bounds__(256) void square_reduce_kernel(
    const unsigned short* __restrict__ Gp, float* __restrict__ out) {
  __shared__ float wsum[4];
  const int t = blockIdx.x >> 5;
  const int seg = blockIdx.x & 31;
  int I = 0, rem = t;
  while (rem >= (TG - I)) { rem -= (TG - I); ++I; }
  const int J = I + rem;

  const int off0 = seg * 2048 + threadIdx.x * 8;
  const unsigned short* base = Gp + (size_t)t * (KSPLIT * BM * BM) + off0;
  float s[8] = {0, 0, 0, 0, 0, 0, 0, 0};
  #pragma unroll
  for (int kc = 0; kc < KSPLIT; ++kc) {
    const ushort8 v = *(const ushort8*)(base + kc * (BM * BM));
    #pragma unroll
    for (int x = 0; x < 8; ++x) s[x] += bf2f(v[x]);
  }

  float local = 0.0f;
  if (I != J) {
    #pragma unroll
    for (int x = 0; x < 8; ++x) local += 2.0f * s[x] * s[x];
  } else {
    #pragma unroll
    for (int x = 0; x < 8; ++x) {
      const int off = off0 + x;
      const int wv = off >> 13;           // wave 0..7
      const int rm = off & 8191;
      const int fi = rm >> 8;             // i*8 + j
      const int l4 = rm & 255;
      const int ln = l4 >> 2, p = l4 & 3;
      const int r = (wv >> 1) * 64 + (fi >> 3) * 16 + (ln >> 4) * 4 + p;
      const int c = (wv & 1) * 128 + (fi & 7) * 16 + (ln & 15);
      const float wgt = (r < c) ? 2.0f : (r == c ? 1.0f : 0.0f);
      local += wgt * s[x] * s[x];
    }
  }
  const float sgn = ((I < 4) == (J < 4)) ? 1.0f : -1.0f;  // q-blocks: < 4
  local *= sgn;

  #pragma unroll
  for (int off = 32; off > 0; off >>= 1) local += __shfl_xor(local, off);
  const int w = threadIdx.x >> 6, lane = threadIdx.x & 63;
  if (lane == 0) wsum[w] = local;
  __syncthreads();
  if (threadIdx.x == 0) {
    const float ts = wsum[0] + wsum[1] + wsum[2] + wsum[3];
    atomicAdd(out, ts * (1.0f / 16773120.0f));  // / (N*(N-1))
  }
}

extern "C" void kernel_launch(void* const* d_in, const int* in_sizes, int n_in,
                              void* d_out, int out_size, void* d_ws, size_t ws_size,
                              hipStream_t stream) {
  const float* fq = (const float*)d_in[0];
  const float* fk = (const float*)d_in[1];
  float* invq = (float*)d_ws;                                    // 16 KiB
  float* invk = invq + N_ROWS;                                   // 16 KiB
  unsigned char* Mt = (unsigned char*)d_ws + 32768;              // 8 MiB fp8
  unsigned short* Gp = (unsigned short*)(Mt + (size_t)2048 * N_ROWS);  // 36 MiB
  float* out = (float*)d_out;

  rownorm_kernel<<<dim3(N_ROWS / 4, 2), 256, 0, stream>>>(fq, fk, invq, invk, out);
  transpose_scale_kernel<<<dim3(16, 32), 256, 0, stream>>>(fq, fk, invq, invk, Mt);
  gram_partial_kernel<<<NJOBS, 512, 0, stream>>>(Mt, Gp);
  square_reduce_kernel<<<NTRI * 32, 256, 0, stream>>>(Gp, out);
}

// Round 13
// 113.978 us; speedup vs baseline: 1.0834x; 1.0834x over previous
//
#include <hip/hip_runtime.h>
#include <stdint.h>

// N=4096, D=1024 -> M = [Q|K] : 4096 x 2048, Mt = M^T (fp8 e4m3, K-permuted)
// loss = [ sum_{a,b} s_a s_b (M^T M)_ab^2 ] / (N*(N-1)), s_a=+1 (a<1024), -1 else
// R13 = exact revert to R11 (champion, 114.7us): 128x128 fp8 gram tiles,
// 256 thr, 32 KiB single-buffered LDS, KSPLIT=8 (4.25 blocks/CU supplied).
// All structural departures (256^2 tiles, grouped tiles, dbuf, fused finish)
// measured worse or neutral in R4,R5,R7,R8,R10,R12.
#define N_ROWS 4096
#define DIMS   1024
#define BM 128
#define BK 128         // fp8 elements per LDS row = 128 bytes
#define TG 16
#define NTRI 136
#define KSPLIT 8
#define KCHUNK 512     // 4096/KSPLIT (fp8 bytes)
#define NJOBS  (NTRI * KSPLIT) // 1088

typedef __attribute__((ext_vector_type(2))) long longx2;
typedef __attribute__((ext_vector_type(4))) float f32x4;

__device__ __forceinline__ unsigned short f2bf(float f) {
  union { float f; unsigned int u; } c; c.f = f;
  unsigned int u = c.u;
  return (unsigned short)((u + 0x7fffu + ((u >> 16) & 1u)) >> 16);
}
__device__ __forceinline__ float bf2f(unsigned short v) {
  union { float f; unsigned int u; } c; c.u = ((unsigned int)v) << 16;
  return c.f;
}
// pack 4 floats -> 4 fp8 e4m3 bytes (hardware cvt, OCP on gfx950)
__device__ __forceinline__ unsigned int pk4_fp8(float a, float b, float c, float d) {
  int v = __builtin_amdgcn_cvt_pk_fp8_f32(a, b, 0, false);
  v = __builtin_amdgcn_cvt_pk_fp8_f32(c, d, v, true);
  return (unsigned int)v;
}
// async global->LDS, 16B/lane
__device__ __forceinline__ void async_cp16(const unsigned char* g, void* lds) {
  __builtin_amdgcn_global_load_lds(
      (const __attribute__((address_space(1))) void*)g,
      (__attribute__((address_space(3))) void*)lds, 16, 0, 0);
}

// ---------------------------------------------------------------------------
// K1: inverse row norms; zero d_out.
// ---------------------------------------------------------------------------
__global__ __launch_bounds__(256) void rownorm_kernel(
    const float* __restrict__ fq, const float* __restrict__ fk,
    float* __restrict__ invq, float* __restrict__ invk, float* __restrict__ out) {
  if (blockIdx.x == 0 && blockIdx.y == 0 && threadIdx.x == 0) out[0] = 0.0f;
  const int w = threadIdx.x >> 6, lane = threadIdx.x & 63;
  const int row = blockIdx.x * 4 + w;
  const float* src = blockIdx.y ? fk : fq;
  float* dst = blockIdx.y ? invk : invq;
  const float4* s4 = (const float4*)(src + (size_t)row * DIMS);
  float ss = 0.0f;
  #pragma unroll
  for (int s = 0; s < 4; ++s) {
    float4 v = s4[lane + 64 * s];
    ss += v.x * v.x + v.y * v.y + v.z * v.z + v.w * v.w;
  }
  #pragma unroll
  for (int off = 32; off > 0; off >>= 1) ss += __shfl_xor(ss, off);
  if (lane == 0) dst[row] = 1.0f / sqrtf(ss);  // eps terms cancel (~3e-9 rel)
}

// ---------------------------------------------------------------------------
// K2: Mt[a][perm(i)] = fp8(normalized), transposed via LDS.
// K-perm: i = s1*64+s0*32+q*8+j -> pos = q*32+s1*16+s0*8+j within 128-block.
// ---------------------------------------------------------------------------
__global__ __launch_bounds__(256) void transpose_scale_kernel(
    const float* __restrict__ fq, const float* __restrict__ fk,
    const float* __restrict__ invq, const float* __restrict__ invk,
    unsigned char* __restrict__ Mt) {
  __shared__ unsigned short tile[64][260];
  const int i0 = blockIdx.x * 256;
  const int a0 = blockIdx.y * 64;
  const int w = threadIdx.x >> 6, lane = threadIdx.x & 63;
  const float* src;
  const float* inv;
  int acol;
  if (a0 < DIMS) { src = fq; inv = invq; acol = a0 + lane; }
  else           { src = fk; inv = invk; acol = a0 - DIMS + lane; }

  for (int c0 = 0; c0 < 64; c0 += 4) {
    ushort4 v;
    unsigned short* vp = (unsigned short*)&v;
    #pragma unroll
    for (int c = 0; c < 4; ++c) {
      const int i = i0 + w * 64 + c0 + c;
      vp[c] = f2bf(src[(size_t)i * DIMS + acol] * inv[i]);
    }
    *(ushort4*)&tile[lane][w * 64 + c0] = v;
  }
  __syncthreads();
  const int il = (lane * 4) & 127;
  const int blk = (i0 + lane * 4) >> 7;
  const int q = (il >> 3) & 3, s0b = (il >> 5) & 1, s1b = (il >> 6) & 1;
  const int pos = q * 32 + s1b * 16 + s0b * 8 + (il & 7);
  #pragma unroll
  for (int r = 0; r < 16; ++r) {
    const int al = w * 16 + r;
    ushort4 v = *(const ushort4*)&tile[al][lane * 4];
    const unsigned int p8 = pk4_fp8(bf2f(v.x), bf2f(v.y), bf2f(v.z), bf2f(v.w));
    *(unsigned int*)(Mt + (size_t)(a0 + al) * N_ROWS + blk * 128 + pos) = p8;
  }
}

// ---------------------------------------------------------------------------
// K3: partial Gram tiles, fp8 MFMA. Single-buffered 32 KiB LDS, natural job
// order, no fences. Stores raw bf16 partial to its slab (sum-before-square
// happens in K4).
// ---------------------------------------------------------------------------
__global__ __launch_bounds__(256, 2) void gram_partial_kernel(
    const unsigned char* __restrict__ Mt, unsigned short* __restrict__ Gp) {
  __shared__ __align__(16) char smem[2 * BM * BK];  // 32 KiB: A + B panels

  const int t = blockIdx.x >> 3;
  const int kc = blockIdx.x & 7;
  int I = 0, rem = t;
  while (rem >= (TG - I)) { rem -= (TG - I); ++I; }
  const int J = I + rem;

  const int tid = threadIdx.x, w = tid >> 6, lane = tid & 63;

  const int isB = w >> 1;
  const int rblk = isB ? J : I;
  const int rl = lane >> 3;
  const int cl = (lane & 7) ^ rl;          // chunk swizzle (verified R1..R12)
  const bool skipStage = (isB && I == J);
  const unsigned char* gsrc0 =
      Mt + (size_t)(rblk * BM + (w & 1) * 64 + rl) * N_ROWS + kc * KCHUNK + cl * 16;
  char* ldsBase = smem + isB * 16384 + (w & 1) * 8192;
  const int bOff = (I == J) ? 0 : 16384;

  const int ml = lane & 15, quad = lane >> 4;
  const int ar0 = (w >> 1) * 64, bc0 = (w & 1) * 64;

  f32x4 acc[4][4] = {};

  for (int kk = 0; kk < KCHUNK; kk += BK) {
    if (!skipStage) {
      const unsigned char* g = gsrc0 + kk;
      #pragma unroll
      for (int s = 0; s < 8; ++s)
        async_cp16(g + (size_t)s * 8 * N_ROWS, ldsBase + s * 1024);
    }
    __syncthreads();
    longx2 a[4][2], b[4][2];
    #pragma unroll
    for (int i = 0; i < 4; ++i) {
      const int ra = (ar0 + i * 16 + ml) * BK;
      const int rb = (bc0 + i * 16 + ml) * BK;
      #pragma unroll
      for (int s1 = 0; s1 < 2; ++s1) {
        const int slot = ((quad * 2 + s1) ^ (ml & 7)) * 16;
        a[i][s1] = *(const longx2*)(smem + ra + slot);
        b[i][s1] = *(const longx2*)(smem + bOff + rb + slot);
      }
    }
    #pragma unroll
    for (int s1 = 0; s1 < 2; ++s1)
      #pragma unroll
      for (int h = 0; h < 2; ++h)
        #pragma unroll
        for (int i = 0; i < 4; ++i)
          #pragma unroll
          for (int j = 0; j < 4; ++j)
            acc[i][j] = __builtin_amdgcn_mfma_f32_16x16x32_fp8_fp8(
                a[i][s1][h], b[j][s1][h], acc[i][j], 0, 0, 0);
    __syncthreads();
  }

  // epilogue: lane-major coalesced bf16 slab (layout consistent across kc)
  unsigned short* slab = Gp + (size_t)blockIdx.x * (BM * BM) + w * 4096;
  #pragma unroll
  for (int i = 0; i < 4; ++i)
    #pragma unroll
    for (int j = 0; j < 4; ++j) {
      ushort4 o;
      o.x = f2bf(acc[i][j][0]); o.y = f2bf(acc[i][j][1]);
      o.z = f2bf(acc[i][j][2]); o.w = f2bf(acc[i][j][3]);
      *(ushort4*)(slab + (i * 4 + j) * 256 + lane * 4) = o;
    }
}

// ---------------------------------------------------------------------------
// K4: sum KSPLIT partials (fp32), square, sign/weight, reduce -> atomicAdd.
// ---------------------------------------------------------------------------
__global__ __launch_bounds__(256) void square_reduce_kernel(
    const unsigned short* __restrict__ Gp, float* __restrict__ out) {
  __shared__ float wsum[4];
  const int t = blockIdx.x >> 3;
  const int seg = blockIdx.x & 7;
  int I = 0, rem = t;
  while (rem >= (TG - I)) { rem -= (TG - I); ++I; }
  const int J = I + rem;

  const unsigned short* base =
      Gp + (size_t)t * (KSPLIT * BM * BM) + seg * 2048 + threadIdx.x * 8;
  float s[8] = {0, 0, 0, 0, 0, 0, 0, 0};
  #pragma unroll
  for (int kc = 0; kc < KSPLIT; ++kc) {
    const ushort4 v0 = *(const ushort4*)(base + kc * (BM * BM));
    const ushort4 v1 = *(const ushort4*)(base + kc * (BM * BM) + 4);
    s[0] += bf2f(v0.x); s[1] += bf2f(v0.y); s[2] += bf2f(v0.z); s[3] += bf2f(v0.w);
    s[4] += bf2f(v1.x); s[5] += bf2f(v1.y); s[6] += bf2f(v1.z); s[7] += bf2f(v1.w);
  }
  float local = 0.0f;
  #pragma unroll
  for (int x = 0; x < 8; ++x) local += s[x] * s[x];

  const float sgn = ((I < 8) == (J < 8)) ? 1.0f : -1.0f;
  local *= (I == J ? 1.0f : 2.0f) * sgn;

  #pragma unroll
  for (int off = 32; off > 0; off >>= 1) local += __shfl_xor(local, off);
  const int w = threadIdx.x >> 6, lane = threadIdx.x & 63;
  if (lane == 0) wsum[w] = local;
  __syncthreads();
  if (threadIdx.x == 0) {
    const float ts = wsum[0] + wsum[1] + wsum[2] + wsum[3];
    atomicAdd(out, ts * (1.0f / 16773120.0f));  // / (N*(N-1))
  }
}

extern "C" void kernel_launch(void* const* d_in, const int* in_sizes, int n_in,
                              void* d_out, int out_size, void* d_ws, size_t ws_size,
                              hipStream_t stream) {
  const float* fq = (const float*)d_in[0];
  const float* fk = (const float*)d_in[1];
  float* invq = (float*)d_ws;                                    // 16 KiB
  float* invk = invq + N_ROWS;                                   // 16 KiB
  unsigned char* Mt = (unsigned char*)d_ws + 32768;              // 8 MiB fp8
  unsigned short* Gp = (unsigned short*)(Mt + (size_t)2048 * N_ROWS);  // 35.7 MiB
  float* out = (float*)d_out;

  rownorm_kernel<<<dim3(N_ROWS / 4, 2), 256, 0, stream>>>(fq, fk, invq, invk, out);
  transpose_scale_kernel<<<dim3(16, 32), 256, 0, stream>>>(fq, fk, invq, invk, Mt);
  gram_partial_kernel<<<NJOBS, 256, 0, stream>>>(Mt, Gp);
  square_reduce_kernel<<<NTRI * 8, 256, 0, stream>>>(Gp, out);
}